// Round 1
// baseline (86.255 us; speedup 1.0000x reference)
//
#include <hip/hip_runtime.h>

// Problem constants (from reference):
//   pcd:  (B=4, N=8192, 3) f32
//   locs: (L=2048, 3) f32   [16x16x8 voxel grid]
//   out:  (B=4, L=2048, T=15) f32, out[b,l,t] = #points with ceil(dist) <= t+1
// ceil(sqrt(d2)) <= T  <=>  d2 <= T*T  (T integer) -> pure compare, no sqrt.

#define BATCH 4
#define NPTS 8192
#define NLOC 2048
#define NT 15
#define SPLITS 16          // point-dim split within a block
#define LOCS_PER_BLOCK 16
#define PPS (NPTS / SPLITS)  // 512 points per thread

__global__ __launch_bounds__(256) void manual_feature_kernel(
    const float* __restrict__ pcd, const float* __restrict__ locs,
    float* __restrict__ out)
{
    const int tid   = threadIdx.x;
    const int li    = tid & (LOCS_PER_BLOCK - 1);
    const int split = tid >> 4;                 // 0..15
    const int b     = blockIdx.x >> 7;          // 0..3
    const int ltile = blockIdx.x & 127;         // 0..127
    const int loc   = ltile * LOCS_PER_BLOCK + li;

    const float lx = locs[loc * 3 + 0];
    const float ly = locs[loc * 3 + 1];
    const float lz = locs[loc * 3 + 2];

    int cnt[NT];
#pragma unroll
    for (int t = 0; t < NT; ++t) cnt[t] = 0;

    const float thr2[NT] = {1.f, 4.f, 9.f, 16.f, 25.f, 36.f, 49.f, 64.f,
                            81.f, 100.f, 121.f, 144.f, 169.f, 196.f, 225.f};

    // This thread's 512-point chunk, read 4 points (12 floats) per iter.
    // float-index (b*NPTS + split*PPS)*3 is divisible by 4 (PPS*3 = 1536).
    const float4* base =
        reinterpret_cast<const float4*>(pcd + (size_t)(b * NPTS + split * PPS) * 3);

#pragma unroll 2
    for (int j = 0; j < PPS / 4; ++j) {
        const float4 f0 = base[j * 3 + 0];
        const float4 f1 = base[j * 3 + 1];
        const float4 f2 = base[j * 3 + 2];
        const float px[4] = {f0.x, f0.w, f1.z, f2.y};
        const float py[4] = {f0.y, f1.x, f1.w, f2.z};
        const float pz[4] = {f0.z, f1.y, f2.x, f2.w};
#pragma unroll
        for (int k = 0; k < 4; ++k) {
            const float dx = px[k] - lx;
            const float dy = py[k] - ly;
            const float dz = pz[k] - lz;
            const float d2 = dx * dx + dy * dy + dz * dz;
#pragma unroll
            for (int t = 0; t < NT; ++t) cnt[t] += (d2 <= thr2[t]) ? 1 : 0;
        }
    }

    // Reduce the 16 splits per loc in LDS; one writer per output element.
    __shared__ int part[256][16];  // [tid][t], padded to 16
#pragma unroll
    for (int t = 0; t < NT; ++t) part[tid][t] = cnt[t];
    __syncthreads();

    if (tid < LOCS_PER_BLOCK * NT) {
        const int li2 = tid / NT;
        const int t   = tid - li2 * NT;
        int s = 0;
#pragma unroll
        for (int k = 0; k < SPLITS; ++k) s += part[k * LOCS_PER_BLOCK + li2][t];
        out[((size_t)b * NLOC + (size_t)(ltile * LOCS_PER_BLOCK + li2)) * NT + t] =
            (float)s;
    }
}

extern "C" void kernel_launch(void* const* d_in, const int* in_sizes, int n_in,
                              void* d_out, int out_size, void* d_ws, size_t ws_size,
                              hipStream_t stream) {
    const float* pcd  = (const float*)d_in[0];
    const float* locs = (const float*)d_in[1];
    float* out = (float*)d_out;
    manual_feature_kernel<<<dim3(BATCH * (NLOC / LOCS_PER_BLOCK)), dim3(256), 0,
                            stream>>>(pcd, locs, out);
}

// Round 2
// 71.608 us; speedup vs baseline: 1.2045x; 1.2045x over previous
//
#include <hip/hip_runtime.h>

// Problem constants (from reference):
//   pcd:  (B=4, N=8192, 3) f32
//   locs: (L=2048, 3) f32   [16x16x8 voxel grid]
//   out:  (B=4, L=2048, T=15) f32, out[b,l,t] = #points with ceil(dist) <= t+1
// ceil(sqrt(d2)) <= T  <=>  d2 <= T*T  (T integer) -> pure compare, no sqrt.

#define BATCH 4
#define NPTS 8192
#define NLOC 2048
#define NT 15
#define SPLITS 64            // point-dim split within a block
#define LOCS_PER_BLOCK 4
#define PPS (NPTS / SPLITS)  // 128 points per thread

__global__ __launch_bounds__(256) void manual_feature_kernel(
    const float* __restrict__ pcd, const float* __restrict__ locs,
    float* __restrict__ out)
{
    const int tid   = threadIdx.x;
    const int li    = tid & (LOCS_PER_BLOCK - 1);   // 0..3
    const int split = tid >> 2;                     // 0..63
    const int b     = blockIdx.x >> 9;              // 0..3
    const int ltile = blockIdx.x & 511;             // 0..511
    const int loc   = ltile * LOCS_PER_BLOCK + li;

    const float lx = locs[loc * 3 + 0];
    const float ly = locs[loc * 3 + 1];
    const float lz = locs[loc * 3 + 2];

    int cnt[NT];
#pragma unroll
    for (int t = 0; t < NT; ++t) cnt[t] = 0;

    const float thr2[NT] = {1.f, 4.f, 9.f, 16.f, 25.f, 36.f, 49.f, 64.f,
                            81.f, 100.f, 121.f, 144.f, 169.f, 196.f, 225.f};

    // This thread's 128-point chunk, read 4 points (12 floats) per iter.
    // float-index (b*NPTS + split*PPS)*3 = multiple of 384 -> float4 aligned.
    const float4* base =
        reinterpret_cast<const float4*>(pcd + (size_t)(b * NPTS + split * PPS) * 3);

#pragma unroll 2
    for (int j = 0; j < PPS / 4; ++j) {
        const float4 f0 = base[j * 3 + 0];
        const float4 f1 = base[j * 3 + 1];
        const float4 f2 = base[j * 3 + 2];
        const float px0 = f0.x, py0 = f0.y, pz0 = f0.z;
        const float px1 = f0.w, py1 = f1.x, pz1 = f1.y;
        const float px2 = f1.z, py2 = f1.w, pz2 = f2.x;
        const float px3 = f2.y, py3 = f2.z, pz3 = f2.w;

        float dx, dy, dz, d2;
#define DO_POINT(PX, PY, PZ)                                      \
        dx = (PX) - lx; dy = (PY) - ly; dz = (PZ) - lz;           \
        d2 = dx * dx + dy * dy + dz * dz;                         \
        _Pragma("unroll")                                         \
        for (int t = 0; t < NT; ++t) cnt[t] += (d2 <= thr2[t]) ? 1 : 0;

        DO_POINT(px0, py0, pz0)
        DO_POINT(px1, py1, pz1)
        DO_POINT(px2, py2, pz2)
        DO_POINT(px3, py3, pz3)
#undef DO_POINT
    }

    // Reduce the 64 splits per loc in LDS; one writer per output element.
    __shared__ int part[256][17];  // stride 17: odd -> conflict-free writes
#pragma unroll
    for (int t = 0; t < NT; ++t) part[tid][t] = cnt[t];
    __syncthreads();

    if (tid < LOCS_PER_BLOCK * NT) {
        const int li2 = tid / NT;       // 0..3
        const int t   = tid - li2 * NT; // 0..14
        int s = 0;
#pragma unroll
        for (int k = 0; k < SPLITS; ++k)
            s += part[k * LOCS_PER_BLOCK + li2][t];
        out[((size_t)b * NLOC + (size_t)(ltile * LOCS_PER_BLOCK + li2)) * NT + t] =
            (float)s;
    }
}

extern "C" void kernel_launch(void* const* d_in, const int* in_sizes, int n_in,
                              void* d_out, int out_size, void* d_ws, size_t ws_size,
                              hipStream_t stream) {
    const float* pcd  = (const float*)d_in[0];
    const float* locs = (const float*)d_in[1];
    float* out = (float*)d_out;
    manual_feature_kernel<<<dim3(BATCH * (NLOC / LOCS_PER_BLOCK)), dim3(256), 0,
                            stream>>>(pcd, locs, out);
}

// Round 3
// 34.421 us; speedup vs baseline: 2.5059x; 2.0804x over previous
//
#include <hip/hip_runtime.h>

// out[b,l,t] = #points with ceil(dist(pcd[b,i], locs[l])) <= t+1, t=0..14
// For non-integer d: ceil(d) <= t+1  <=>  trunc(d) <= t.
// Per point: f = trunc(sqrt(d2)); histogram h[f] (f<16); cnt[t] = prefix(h)[t].
// Histogram packed: u64 acc of 16x4-bit fields (batch of 8 points),
// folded into 4x u32 byte-field accumulators (capacity 128 pts/thread).

#define BATCH 4
#define NPTS 8192
#define NLOC 2048
#define NT 15
#define SPLITS 64            // point-dim split within a block
#define LOCS_PER_BLOCK 4
#define PPS (NPTS / SPLITS)  // 128 points per thread

__global__ __launch_bounds__(256) void manual_feature_kernel(
    const float* __restrict__ pcd, const float* __restrict__ locs,
    float* __restrict__ out)
{
    const int tid   = threadIdx.x;
    const int li    = tid & (LOCS_PER_BLOCK - 1);   // 0..3
    const int split = tid >> 2;                     // 0..63
    const int b     = blockIdx.x >> 9;              // 0..3
    const int ltile = blockIdx.x & 511;             // 0..511
    const int loc   = ltile * LOCS_PER_BLOCK + li;

    const float lx = locs[loc * 3 + 0];
    const float ly = locs[loc * 3 + 1];
    const float lz = locs[loc * 3 + 2];

    // byte-field histogram accumulators:
    // h2[0]: buckets 0,2,4,6  h2[1]: 1,3,5,7  h2[2]: 8,10,12,14  h2[3]: 9,11,13,15
    unsigned int h2[4] = {0u, 0u, 0u, 0u};

    // This thread's 128-point chunk; float-index (b*NPTS+split*PPS)*3 is
    // a multiple of 384 -> float4 aligned.
    const float4* base =
        reinterpret_cast<const float4*>(pcd + (size_t)(b * NPTS + split * PPS) * 3);

#pragma unroll 2
    for (int batch = 0; batch < PPS / 8; ++batch) {
        unsigned long long acc = 0ull;  // 16 x 4-bit buckets, <=8 adds: no overflow
#pragma unroll
        for (int j = 0; j < 2; ++j) {
            const int idx = batch * 6 + j * 3;
            const float4 f0 = base[idx + 0];
            const float4 f1 = base[idx + 1];
            const float4 f2 = base[idx + 2];

            float dx, dy, dz, d2, d;
            unsigned int f;
#if __has_builtin(__builtin_amdgcn_sqrtf)
#define FAST_SQRT(x) __builtin_amdgcn_sqrtf(x)
#else
#define FAST_SQRT(x) sqrtf(x)
#endif
#define DO_POINT(PX, PY, PZ)                                        \
            dx = (PX) - lx; dy = (PY) - ly; dz = (PZ) - lz;         \
            d2 = dx * dx + dy * dy + dz * dz;                       \
            d  = FAST_SQRT(d2);                                     \
            f  = (unsigned int)d; /* trunc; d in [0,~45] */         \
            acc += (f < 16u) ? (1ull << (4u * f)) : 0ull;

            DO_POINT(f0.x, f0.y, f0.z)
            DO_POINT(f0.w, f1.x, f1.y)
            DO_POINT(f1.z, f1.w, f2.x)
            DO_POINT(f2.y, f2.z, f2.w)
#undef DO_POINT
        }
        const unsigned int lo = (unsigned int)acc;
        const unsigned int hi = (unsigned int)(acc >> 32);
        h2[0] += lo & 0x0F0F0F0Fu;
        h2[1] += (lo >> 4) & 0x0F0F0F0Fu;
        h2[2] += hi & 0x0F0F0F0Fu;
        h2[3] += (hi >> 4) & 0x0F0F0F0Fu;
    }

    // Unpack 16 byte counters -> prefix sums; part[tid][t] = #(f <= t).
    unsigned int h[16];
#pragma unroll
    for (int j = 0; j < 16; ++j) {
        const unsigned int word = h2[(j & 1) + ((j >> 3) << 1)];
        h[j] = (word >> (8 * ((j >> 1) & 3))) & 0xFFu;
    }

    __shared__ int part[256][17];  // stride 17: conflict-light
    unsigned int p = 0;
#pragma unroll
    for (int t = 0; t < NT; ++t) { p += h[t]; part[tid][t] = (int)p; }
    __syncthreads();

    // Reduce the 64 splits per loc; one writer per output element.
    if (tid < LOCS_PER_BLOCK * NT) {
        const int li2 = tid / NT;       // 0..3
        const int t   = tid - li2 * NT; // 0..14
        int s = 0;
#pragma unroll
        for (int k = 0; k < SPLITS; ++k)
            s += part[k * LOCS_PER_BLOCK + li2][t];
        out[((size_t)b * NLOC + (size_t)(ltile * LOCS_PER_BLOCK + li2)) * NT + t] =
            (float)s;
    }
}

extern "C" void kernel_launch(void* const* d_in, const int* in_sizes, int n_in,
                              void* d_out, int out_size, void* d_ws, size_t ws_size,
                              hipStream_t stream) {
    const float* pcd  = (const float*)d_in[0];
    const float* locs = (const float*)d_in[1];
    float* out = (float*)d_out;
    manual_feature_kernel<<<dim3(BATCH * (NLOC / LOCS_PER_BLOCK)), dim3(256), 0,
                            stream>>>(pcd, locs, out);
}

// Round 4
// 30.222 us; speedup vs baseline: 2.8540x; 1.1389x over previous
//
#include <hip/hip_runtime.h>

// out[b,l,t] = #points with ceil(dist(pcd[b,i], locs[l])) <= t+1, t=0..14
// For non-integer d: ceil(d) <= t+1  <=>  trunc(d) <= t.
// Per point: f = min(trunc(sqrt(d2)), 15); histogram h[f]; cnt[t] = prefix(h)[t].
// Bucket 15 is a garbage sink (never read): clamping replaces the f<16 guard.
// Histogram packed: u64 of 16x4-bit fields; dual accumulators (even/odd points)
// halve the serial add chain; nibble budget per acc <= 4, sum <= 8 (safe);
// folded into 4x u32 byte-field accumulators (capacity 128 pts/thread <= 255).

#define BATCH 4
#define NPTS 8192
#define NLOC 2048
#define NT 15
#define SPLITS 64            // point-dim split within a block
#define LOCS_PER_BLOCK 4
#define PPS (NPTS / SPLITS)  // 128 points per thread

#if __has_builtin(__builtin_amdgcn_sqrtf)
#define FAST_SQRT(x) __builtin_amdgcn_sqrtf(x)
#else
#define FAST_SQRT(x) sqrtf(x)
#endif

__global__ __launch_bounds__(256) void manual_feature_kernel(
    const float* __restrict__ pcd, const float* __restrict__ locs,
    float* __restrict__ out)
{
    const int tid   = threadIdx.x;
    const int li    = tid & (LOCS_PER_BLOCK - 1);   // 0..3
    const int split = tid >> 2;                     // 0..63
    const int b     = blockIdx.x >> 9;              // 0..3
    const int ltile = blockIdx.x & 511;             // 0..511
    const int loc   = ltile * LOCS_PER_BLOCK + li;

    const float lx = locs[loc * 3 + 0];
    const float ly = locs[loc * 3 + 1];
    const float lz = locs[loc * 3 + 2];

    // byte-field histogram accumulators:
    // h2[0]: buckets 0,2,4,6  h2[1]: 1,3,5,7  h2[2]: 8,10,12,14  h2[3]: 9,11,13,15
    unsigned int h2[4] = {0u, 0u, 0u, 0u};

    // This thread's 128-point chunk; float-index (b*NPTS+split*PPS)*3 is
    // a multiple of 384 -> float4 aligned.
    const float4* base =
        reinterpret_cast<const float4*>(pcd + (size_t)(b * NPTS + split * PPS) * 3);

#pragma unroll 4
    for (int bt = 0; bt < PPS / 8; ++bt) {
        const float4 f0 = base[bt * 6 + 0];
        const float4 f1 = base[bt * 6 + 1];
        const float4 f2 = base[bt * 6 + 2];
        const float4 f3 = base[bt * 6 + 3];
        const float4 f4 = base[bt * 6 + 4];
        const float4 f5 = base[bt * 6 + 5];

        unsigned long long acc0 = 0ull, acc1 = 0ull;
        {
            float dx, dy, dz, d2, d;
            unsigned int f;
#define DO_POINT(A, PX, PY, PZ)                                     \
            dx = (PX) - lx; dy = (PY) - ly; dz = (PZ) - lz;         \
            d2 = dx * dx + dy * dy + dz * dz;                       \
            d  = FAST_SQRT(d2);                                     \
            f  = (unsigned int)d;                                   \
            f  = (f < 15u) ? f : 15u;                               \
            A += 1ull << (4u * f);

            DO_POINT(acc0, f0.x, f0.y, f0.z)   // p0
            DO_POINT(acc1, f0.w, f1.x, f1.y)   // p1
            DO_POINT(acc0, f1.z, f1.w, f2.x)   // p2
            DO_POINT(acc1, f2.y, f2.z, f2.w)   // p3
            DO_POINT(acc0, f3.x, f3.y, f3.z)   // p4
            DO_POINT(acc1, f3.w, f4.x, f4.y)   // p5
            DO_POINT(acc0, f4.z, f4.w, f5.x)   // p6
            DO_POINT(acc1, f5.y, f5.z, f5.w)   // p7
#undef DO_POINT
        }
        const unsigned long long acc = acc0 + acc1;  // nibbles <= 8, no carry
        const unsigned int lo = (unsigned int)acc;
        const unsigned int hi = (unsigned int)(acc >> 32);
        h2[0] += lo & 0x0F0F0F0Fu;
        h2[1] += (lo >> 4) & 0x0F0F0F0Fu;
        h2[2] += hi & 0x0F0F0F0Fu;
        h2[3] += (hi >> 4) & 0x0F0F0F0Fu;
    }

    // Unpack 16 byte counters -> prefix sums; part[tid][t] = #(f <= t).
    unsigned int h[16];
#pragma unroll
    for (int j = 0; j < 16; ++j) {
        const unsigned int word = h2[(j & 1) + ((j >> 3) << 1)];
        h[j] = (word >> (8 * ((j >> 1) & 3))) & 0xFFu;
    }

    __shared__ int part[256][17];  // stride 17: conflict-light
    unsigned int p = 0;
#pragma unroll
    for (int t = 0; t < NT; ++t) { p += h[t]; part[tid][t] = (int)p; }
    __syncthreads();

    // Reduce the 64 splits per loc; one writer per output element.
    if (tid < LOCS_PER_BLOCK * NT) {
        const int li2 = tid / NT;       // 0..3
        const int t   = tid - li2 * NT; // 0..14
        int s = 0;
#pragma unroll
        for (int k = 0; k < SPLITS; ++k)
            s += part[k * LOCS_PER_BLOCK + li2][t];
        out[((size_t)b * NLOC + (size_t)(ltile * LOCS_PER_BLOCK + li2)) * NT + t] =
            (float)s;
    }
}

extern "C" void kernel_launch(void* const* d_in, const int* in_sizes, int n_in,
                              void* d_out, int out_size, void* d_ws, size_t ws_size,
                              hipStream_t stream) {
    const float* pcd  = (const float*)d_in[0];
    const float* locs = (const float*)d_in[1];
    float* out = (float*)d_out;
    manual_feature_kernel<<<dim3(BATCH * (NLOC / LOCS_PER_BLOCK)), dim3(256), 0,
                            stream>>>(pcd, locs, out);
}